// Round 1
// baseline (82.628 us; speedup 1.0000x reference)
//
#include <hip/hip_runtime.h>
#include <hip/hip_bf16.h>

// Problem constants (fixed-shape problem: B=64, T=2048, D=U=128)
#define DD 128      // feature dim D
#define UU 128      // hidden dim U
#define SEQ_T 2048
#define ROWS 128    // (b,t) rows per block
#define KC 16       // W d-rows staged per chunk
#define PART_STRIDE 132  // per-block partial record: [m, l, pad, pad, ctx[128]]

__device__ __forceinline__ float fast_tanh(float v) {
  float a = fabsf(v);
  float e = __expf(-2.0f * a);
  float r = __fdividef(1.0f - e, 1.0f + e);
  return copysignf(r, v);
}

// Fused: h = tanh(x@(W1+W2)+b1+b2); s = h@V; block-local softmax partial +
// partial context from the LDS-resident x tile. One block = 128 rows of (b,t).
__global__ __launch_bounds__(256, 2)
void fused_score_ctx(const float* __restrict__ x,
                     const float* __restrict__ W1w, const float* __restrict__ W1b,
                     const float* __restrict__ W2w, const float* __restrict__ W2b,
                     const float* __restrict__ Vw,
                     float* __restrict__ part)
{
  __shared__ __align__(16) float xs[ROWS * DD];   // x tile, 16B-granule XOR-swizzled
  __shared__ __align__(16) float wsc[KC * UU];    // W1+W2 chunk
  __shared__ float bsum[UU];
  __shared__ float vv[UU];
  __shared__ float slds[ROWS];
  __shared__ float pctx[2 * DD];
  __shared__ float red[8];

  const int tid = threadIdx.x;
  const int blk = blockIdx.x;
  const int rowbase = blk * ROWS;

  const int tx = tid & 15;   // u-dim lanes (16)
  const int ty = tid >> 4;   // row-dim (16), 8 rows each
  const int tys = ty & 7;    // swizzle key: (row>>3)&7 == ty&7 for rows ty*8+i

  if (tid < UU) { bsum[tid] = W1b[tid] + W2b[tid]; vv[tid] = Vw[tid]; }

  // ---- stage x tile once (read x from HBM exactly once per element) ----
  #pragma unroll
  for (int k = 0; k < 16; ++k) {
    int F = tid + 256 * k;
    int row = F >> 5;
    int g = F & 31;                      // 16B granule within row
    const float4 v = *reinterpret_cast<const float4*>(
        x + (size_t)(rowbase + row) * DD + g * 4);
    int gs = g ^ ((row >> 3) & 7);       // XOR-swizzle within aligned 8-granule groups
    *reinterpret_cast<float4*>(xs + row * DD + gs * 4) = v;
  }

  // per-thread 8 rows x 8 u accumulator; u set = {tx*4..+3} U {64+tx*4..+3}
  float acc[8][8];
  #pragma unroll
  for (int i = 0; i < 8; ++i)
    #pragma unroll
    for (int j = 0; j < 8; ++j) acc[i][j] = 0.0f;

  for (int kc = 0; kc < DD / KC; ++kc) {
    __syncthreads();   // xs ready (kc=0) / previous chunk compute done
    // stage W chunk: (W1+W2)[kc*16 .. +15][0..127]
    #pragma unroll
    for (int k = 0; k < (KC * UU) / (256 * 4); ++k) {  // 2 iters
      int F = tid + 256 * k;
      int dl = F >> 5;
      int g = F & 31;
      size_t off = (size_t)(kc * KC + dl) * UU + g * 4;
      const float4 a = *reinterpret_cast<const float4*>(W1w + off);
      const float4 b = *reinterpret_cast<const float4*>(W2w + off);
      float4 s; s.x = a.x + b.x; s.y = a.y + b.y; s.z = a.z + b.z; s.w = a.w + b.w;
      *reinterpret_cast<float4*>(wsc + dl * UU + g * 4) = s;
    }
    __syncthreads();

    #pragma unroll
    for (int dg = 0; dg < KC / 4; ++dg) {      // 4 d-granules per chunk
      float4 xr[8];
      #pragma unroll
      for (int i = 0; i < 8; ++i) {
        int r = ty * 8 + i;
        int gg = (kc * (KC / 4) + dg) ^ tys;   // swizzled granule index
        xr[i] = *reinterpret_cast<const float4*>(xs + r * DD + gg * 4);
      }
      #pragma unroll
      for (int dd = 0; dd < 4; ++dd) {
        int dl = dg * 4 + dd;
        const float4 w0 = *reinterpret_cast<const float4*>(wsc + dl * UU + tx * 4);
        const float4 w1 = *reinterpret_cast<const float4*>(wsc + dl * UU + 64 + tx * 4);
        #pragma unroll
        for (int i = 0; i < 8; ++i) {
          float xv = (dd == 0) ? xr[i].x : (dd == 1) ? xr[i].y
                   : (dd == 2) ? xr[i].z : xr[i].w;
          acc[i][0] = fmaf(xv, w0.x, acc[i][0]);
          acc[i][1] = fmaf(xv, w0.y, acc[i][1]);
          acc[i][2] = fmaf(xv, w0.z, acc[i][2]);
          acc[i][3] = fmaf(xv, w0.w, acc[i][3]);
          acc[i][4] = fmaf(xv, w1.x, acc[i][4]);
          acc[i][5] = fmaf(xv, w1.y, acc[i][5]);
          acc[i][6] = fmaf(xv, w1.z, acc[i][6]);
          acc[i][7] = fmaf(xv, w1.w, acc[i][7]);
        }
      }
    }
  }

  // ---- epilogue: scores s = V . tanh(h + bias) ----
  float bs[8], vs[8];
  #pragma unroll
  for (int j = 0; j < 8; ++j) {
    int u = (j < 4) ? (tx * 4 + j) : (64 + tx * 4 + (j - 4));
    bs[j] = bsum[u];
    vs[j] = vv[u];
  }
  #pragma unroll
  for (int i = 0; i < 8; ++i) {
    float p = 0.0f;
    #pragma unroll
    for (int j = 0; j < 8; ++j) p += fast_tanh(acc[i][j] + bs[j]) * vs[j];
    // reduce over the 16 tx lanes (stay within 16-lane group of the wave)
    p += __shfl_xor(p, 1);
    p += __shfl_xor(p, 2);
    p += __shfl_xor(p, 4);
    p += __shfl_xor(p, 8);
    if (tx == 0) slds[ty * 8 + i] = p;
  }
  __syncthreads();

  // ---- block-local softmax stats (m, l) ----
  float sv = slds[tid & 127];
  float m = sv;
  #pragma unroll
  for (int off = 1; off < 64; off <<= 1) m = fmaxf(m, __shfl_xor(m, off));
  if ((tid & 63) == 0) red[tid >> 6] = m;
  __syncthreads();
  m = fmaxf(fmaxf(red[0], red[1]), fmaxf(red[2], red[3]));

  float e = (tid < 128) ? __expf(sv - m) : 0.0f;  // count each row once
  float l = e;
  #pragma unroll
  for (int off = 1; off < 64; off <<= 1) l += __shfl_xor(l, off);
  if ((tid & 63) == 0) red[4 + (tid >> 6)] = l;
  __syncthreads();
  l = (red[4] + red[5]) + (red[6] + red[7]);

  if (tid < 128) slds[tid] = e;   // overwrite scores with unnormalized weights
  __syncthreads();

  // ---- partial context from LDS x tile ----
  const int d = tid & 127;
  const int half = tid >> 7;
  const int dg2 = d >> 2, dd2 = d & 3;
  float ca = 0.0f;
  #pragma unroll 8
  for (int k = 0; k < 64; ++k) {
    int t = half * 64 + k;
    float wgt = slds[t];                 // wave-uniform broadcast
    int gs = dg2 ^ ((t >> 3) & 7);
    ca = fmaf(wgt, xs[t * DD + gs * 4 + dd2], ca);
  }
  pctx[half * 128 + d] = ca;
  __syncthreads();

  float* prec = part + (size_t)blk * PART_STRIDE;
  if (tid < 128) prec[4 + tid] = pctx[tid] + pctx[128 + tid];
  if (tid == 0) { prec[0] = m; prec[1] = l; }
}

// Flash-style combine of the 16 per-block partials of each batch row.
__global__ void combine_kernel(const float* __restrict__ part,
                               float* __restrict__ out, int chunks)
{
  int b = blockIdx.x;
  int d = threadIdx.x;  // 128
  float mg = -3.0e38f;
  for (int i = 0; i < chunks; ++i)
    mg = fmaxf(mg, part[(size_t)(b * chunks + i) * PART_STRIDE]);
  float den = 0.0f, num = 0.0f;
  for (int i = 0; i < chunks; ++i) {
    const float* p = part + (size_t)(b * chunks + i) * PART_STRIDE;
    float sc = __expf(p[0] - mg);
    den = fmaf(sc, p[1], den);
    num = fmaf(sc, p[4 + d], num);
  }
  out[(size_t)b * DD + d] = __fdividef(num, den);
}

extern "C" void kernel_launch(void* const* d_in, const int* in_sizes, int n_in,
                              void* d_out, int out_size, void* d_ws, size_t ws_size,
                              hipStream_t stream)
{
  const float* x   = (const float*)d_in[0];
  const float* W1w = (const float*)d_in[1];
  const float* W1b = (const float*)d_in[2];
  const float* W2w = (const float*)d_in[3];
  const float* W2b = (const float*)d_in[4];
  const float* Vw  = (const float*)d_in[5];
  // d_in[6] = V_b: additive constant on scores, cancels in softmax.

  const int bt = in_sizes[0] / DD;   // 131072 rows
  const int nblk = bt / ROWS;        // 1024
  const int B = bt / SEQ_T;          // 64
  const int chunks = SEQ_T / ROWS;   // 16

  float* part = (float*)d_ws;        // nblk * PART_STRIDE floats (~540 KB)

  fused_score_ctx<<<nblk, 256, 0, stream>>>(x, W1w, W1b, W2w, W2b, Vw, part);
  combine_kernel<<<B, 128, 0, stream>>>(part, (float*)d_out, chunks);
}

// Round 2
// 44.682 us; speedup vs baseline: 1.8493x; 1.8493x over previous
//
#include <hip/hip_runtime.h>
#include <hip/hip_bf16.h>

// B=64, T=2048, D=U=128 (fixed shape)
#define DD 128
#define UU 128
#define SEQ_T 2048
#define ROWS 128
#define PART_STRIDE 132  // per-block partial: [m, l, pad, pad, ctx[128]]

typedef __attribute__((ext_vector_type(8))) short short8;   // 8 bf16 (4 VGPR)
typedef __attribute__((ext_vector_type(4))) float f32x4;    // MFMA C/D

__device__ __forceinline__ unsigned short f2bf(float f) {   // RNE fp32->bf16
  unsigned u = __float_as_uint(f);
  u += 0x7fffu + ((u >> 16) & 1u);
  return (unsigned short)(u >> 16);
}
__device__ __forceinline__ float bf2f(unsigned short s) {
  return __uint_as_float(((unsigned)s) << 16);
}
__device__ __forceinline__ float fast_tanh(float v) {
  // tanh(v) = 1 - 2/(e^{2v}+1); branchless, exact at +/-inf
  float z = __expf(2.0f * v);
  return 1.0f - __fdividef(2.0f, z + 1.0f);
}

// One-shot: Wt[u][d] = bf16(W1[d][u] + W2[d][u]); bias[u] = b1[u]+b2[u]
__global__ void prep_kernel(const float* __restrict__ W1w, const float* __restrict__ W1b,
                            const float* __restrict__ W2w, const float* __restrict__ W2b,
                            unsigned short* __restrict__ wt_g, float* __restrict__ bias_g)
{
  int i = blockIdx.x * 256 + threadIdx.x;   // 16384 = 128*128
  int u = i >> 7, d = i & 127;
  float s = W1w[(size_t)d * UU + u] + W2w[(size_t)d * UU + u];
  wt_g[(size_t)u * DD + d] = f2bf(s);
  if (i < UU) bias_g[i] = W1b[i] + W2b[i];
}

// Fused: h = tanh(x@Wsum + bias); s = h@V; block softmax partial + context.
// 128 rows per block, 4 waves; MFMA 16x16x32 bf16, LDS granule-XOR swizzle.
__global__ __launch_bounds__(256, 2)
void fused_score_ctx(const float* __restrict__ x,
                     const unsigned short* __restrict__ wt_g,
                     const float* __restrict__ bias_g,
                     const float* __restrict__ Vw,
                     float* __restrict__ part)
{
  __shared__ __align__(16) unsigned short xs[ROWS * DD];  // 32 KB, swizzled bf16
  __shared__ __align__(16) unsigned short wt[UU * DD];    // 32 KB, swizzled bf16 (u-major)
  __shared__ float bsum[UU];
  __shared__ float vv[UU];
  __shared__ float slds[ROWS];
  __shared__ float pctx[2 * DD];
  __shared__ float red[8];

  const int tid = threadIdx.x;
  const int blk = blockIdx.x;
  const int rowbase = blk * ROWS;

  if (tid < UU) { bsum[tid] = bias_g[tid]; vv[tid] = Vw[tid]; }

  // ---- stage x (fp32 -> bf16, XOR-swizzled granules of 8 elems) ----
  #pragma unroll
  for (int it = 0; it < 8; ++it) {
    int F = tid + 256 * it;            // 2048 granules
    int row = F >> 4, g = F & 15;
    const float* src = x + (size_t)(rowbase + row) * DD + g * 8;
    const float4 v0 = *reinterpret_cast<const float4*>(src);
    const float4 v1 = *reinterpret_cast<const float4*>(src + 4);
    short8 pk;
    pk[0] = (short)f2bf(v0.x); pk[1] = (short)f2bf(v0.y);
    pk[2] = (short)f2bf(v0.z); pk[3] = (short)f2bf(v0.w);
    pk[4] = (short)f2bf(v1.x); pk[5] = (short)f2bf(v1.y);
    pk[6] = (short)f2bf(v1.z); pk[7] = (short)f2bf(v1.w);
    *reinterpret_cast<short8*>(xs + row * DD + ((g ^ (row & 15)) << 3)) = pk;
  }
  // ---- stage Wt (bf16 linear -> swizzled LDS) ----
  #pragma unroll
  for (int it = 0; it < 8; ++it) {
    int F = tid + 256 * it;
    int u = F >> 4, g = F & 15;
    short8 wv = *reinterpret_cast<const short8*>(wt_g + (size_t)F * 8);
    *reinterpret_cast<short8*>(wt + u * DD + ((g ^ (u & 15)) << 3)) = wv;
  }
  __syncthreads();

  // ---- MFMA GEMM: per wave 32 rows x 128 u ----
  const int w = tid >> 6, l = tid & 63, lx = l & 15, lq = l >> 4;
  f32x4 acc[2][8];
  #pragma unroll
  for (int mf = 0; mf < 2; ++mf)
    #pragma unroll
    for (int nf = 0; nf < 8; ++nf) acc[mf][nf] = (f32x4){0.f, 0.f, 0.f, 0.f};

  const int arow0 = w * 32 + lx;
  #pragma unroll
  for (int kf = 0; kf < 4; ++kf) {
    const int gs8 = ((kf * 4 + lq) ^ lx) << 3;   // swizzled granule byte/2 offset
    short8 a0 = *reinterpret_cast<const short8*>(xs + arow0 * DD + gs8);
    short8 a1 = *reinterpret_cast<const short8*>(xs + (arow0 + 16) * DD + gs8);
    short8 b[8];
    #pragma unroll
    for (int nf = 0; nf < 8; ++nf)
      b[nf] = *reinterpret_cast<const short8*>(wt + (nf * 16 + lx) * DD + gs8);
    #pragma unroll
    for (int nf = 0; nf < 8; ++nf) {
      acc[0][nf] = __builtin_amdgcn_mfma_f32_16x16x32_bf16(a0, b[nf], acc[0][nf], 0, 0, 0);
      acc[1][nf] = __builtin_amdgcn_mfma_f32_16x16x32_bf16(a1, b[nf], acc[1][nf], 0, 0, 0);
    }
  }

  // ---- scores: s[row] = sum_u V[u] * tanh(h[row][u] + bias[u]) ----
  float vs[8], bs[8];
  #pragma unroll
  for (int nf = 0; nf < 8; ++nf) { vs[nf] = vv[nf * 16 + lx]; bs[nf] = bsum[nf * 16 + lx]; }
  #pragma unroll
  for (int mf = 0; mf < 2; ++mf) {
    #pragma unroll
    for (int r = 0; r < 4; ++r) {
      float p = 0.0f;
      #pragma unroll
      for (int nf = 0; nf < 8; ++nf)
        p += vs[nf] * fast_tanh(acc[mf][nf][r] + bs[nf]);
      p += __shfl_xor(p, 1);
      p += __shfl_xor(p, 2);
      p += __shfl_xor(p, 4);
      p += __shfl_xor(p, 8);
      if (lx == 0) slds[w * 32 + mf * 16 + lq * 4 + r] = p;  // C/D row=(lq*4+r)
    }
  }
  __syncthreads();

  // ---- block-local softmax stats (m, l) ----
  float sv = slds[tid & 127];
  float m = sv;
  #pragma unroll
  for (int off = 1; off < 64; off <<= 1) m = fmaxf(m, __shfl_xor(m, off));
  if ((tid & 63) == 0) red[tid >> 6] = m;
  __syncthreads();
  m = fmaxf(fmaxf(red[0], red[1]), fmaxf(red[2], red[3]));

  float e = (tid < 128) ? __expf(sv - m) : 0.0f;  // each row counted once
  float lsum = e;
  #pragma unroll
  for (int off = 1; off < 64; off <<= 1) lsum += __shfl_xor(lsum, off);
  if ((tid & 63) == 0) red[4 + (tid >> 6)] = lsum;
  __syncthreads();
  lsum = (red[4] + red[5]) + (red[6] + red[7]);

  if (tid < 128) slds[tid] = e;
  __syncthreads();

  // ---- partial context from swizzled bf16 x tile ----
  const int d = tid & 127, half = tid >> 7;
  const int gd = d >> 3, el = d & 7;
  float ca = 0.0f;
  #pragma unroll 8
  for (int k = 0; k < 64; ++k) {
    int t = half * 64 + k;
    float wgt = slds[t];   // wave-uniform broadcast
    ca = fmaf(wgt, bf2f(xs[t * DD + (((gd ^ (t & 15)) << 3) + el)]), ca);
  }
  pctx[half * 128 + d] = ca;
  __syncthreads();

  float* prec = part + (size_t)blk * PART_STRIDE;
  if (tid < 128) prec[4 + tid] = pctx[tid] + pctx[128 + tid];
  if (tid == 0) { prec[0] = m; prec[1] = lsum; }
}

// Flash-style combine of 16 per-block partials per batch row.
__global__ void combine_kernel(const float* __restrict__ part,
                               float* __restrict__ out, int chunks)
{
  int b = blockIdx.x;
  int d = threadIdx.x;  // 128
  float mg = -3.0e38f;
  for (int i = 0; i < chunks; ++i)
    mg = fmaxf(mg, part[(size_t)(b * chunks + i) * PART_STRIDE]);
  float den = 0.0f, num = 0.0f;
  for (int i = 0; i < chunks; ++i) {
    const float* p = part + (size_t)(b * chunks + i) * PART_STRIDE;
    float sc = __expf(p[0] - mg);
    den = fmaf(sc, p[1], den);
    num = fmaf(sc, p[4 + d], num);
  }
  out[(size_t)b * DD + d] = __fdividef(num, den);
}

extern "C" void kernel_launch(void* const* d_in, const int* in_sizes, int n_in,
                              void* d_out, int out_size, void* d_ws, size_t ws_size,
                              hipStream_t stream)
{
  const float* x   = (const float*)d_in[0];
  const float* W1w = (const float*)d_in[1];
  const float* W1b = (const float*)d_in[2];
  const float* W2w = (const float*)d_in[3];
  const float* W2b = (const float*)d_in[4];
  const float* Vw  = (const float*)d_in[5];
  // d_in[6] = V_b: constant on scores, cancels in softmax.

  const int bt = in_sizes[0] / DD;   // 131072
  const int nblk = bt / ROWS;        // 1024
  const int B = bt / SEQ_T;          // 64
  const int chunks = SEQ_T / ROWS;   // 16

  float* part = (float*)d_ws;                                        // 540672 B
  unsigned short* wt_g = (unsigned short*)((char*)d_ws + 540672);    // 32768 B
  float* bias_g = (float*)((char*)d_ws + 540672 + 32768);            // 512 B

  prep_kernel<<<64, 256, 0, stream>>>(W1w, W1b, W2w, W2b, wt_g, bias_g);
  fused_score_ctx<<<nblk, 256, 0, stream>>>(x, wt_g, bias_g, Vw, part);
  combine_kernel<<<B, 128, 0, stream>>>(part, (float*)d_out, chunks);
}